// Round 4
// baseline (2878.551 us; speedup 1.0000x reference)
//
#include <hip/hip_runtime.h>

// ---------------------------------------------------------------------------
// Sparse 3D U-Net forward (MI355X / gfx950), f32.
// Conv structure: lane = output channel, slots processed slot-serially per
// wave (SB slots / stream). Weights: coalesced per-lane vector loads, reused
// across slots. Inputs: wave-uniform broadcast loads (scalar-cached). Tap and
// slot validity via ballot -> scalar mask -> s_cbranch skips (no masked-lane
// FMA waste). Invalid gathers read a zero row at slot index `cap`.
// ---------------------------------------------------------------------------

#define NVOX 100
#define EPSB 1e-4f
typedef unsigned long long u64;
#define DEVFN __device__ __forceinline__

// Accumulate CIN channels of one tap for SB slots (per stream).
// lane = output channel (COUT<=64: lane, COUT==96: lane & lane+64 tail,
// HALVES==2: two slot streams, channel = lane&31).
template<int CIN, int COUT, int SB, int HALVES>
DEVFN void ci_fma(const float* __restrict__ in, const float* __restrict__ wTap,
                  u64 m2, int lane, const int (&ns0)[SB], const int (&ns1)[SB],
                  float (&acc)[SB], float (&acc2)[SB])
{
    constexpr bool TAIL = (COUT > 64);
    const int cl = (HALVES == 2) ? (lane & 31) : lane;
    const float* rp[SB];
#pragma unroll
    for (int s = 0; s < SB; ++s) {
        if constexpr (HALVES == 2) {
            const int nsel = (lane < 32) ? ns0[s] : ns1[s];
            rp[s] = in + (size_t)nsel * CIN;
        } else {
            rp[s] = in + (size_t)ns0[s] * CIN;
        }
    }
#pragma unroll 1
    for (int c0 = 0; c0 < CIN; c0 += 8) {
        float wv[8];
        float wv2[8];
#pragma unroll
        for (int j = 0; j < 8; ++j) {
            wv[j] = wTap[(c0 + j) * COUT + cl];
            if constexpr (TAIL)
                wv2[j] = (lane < 32) ? wTap[(c0 + j) * COUT + 64 + lane] : 0.f;
        }
#pragma unroll
        for (int s = 0; s < SB; ++s) {
            if (!((m2 >> s) & 1)) continue;
            const float4 a = *reinterpret_cast<const float4*>(rp[s] + c0);
            const float4 b = *reinterpret_cast<const float4*>(rp[s] + c0 + 4);
            acc[s] = fmaf(a.x, wv[0], acc[s]);
            acc[s] = fmaf(a.y, wv[1], acc[s]);
            acc[s] = fmaf(a.z, wv[2], acc[s]);
            acc[s] = fmaf(a.w, wv[3], acc[s]);
            acc[s] = fmaf(b.x, wv[4], acc[s]);
            acc[s] = fmaf(b.y, wv[5], acc[s]);
            acc[s] = fmaf(b.z, wv[6], acc[s]);
            acc[s] = fmaf(b.w, wv[7], acc[s]);
            if constexpr (TAIL) {
                acc2[s] = fmaf(a.x, wv2[0], acc2[s]);
                acc2[s] = fmaf(a.y, wv2[1], acc2[s]);
                acc2[s] = fmaf(a.z, wv2[2], acc2[s]);
                acc2[s] = fmaf(a.w, wv2[3], acc2[s]);
                acc2[s] = fmaf(b.x, wv2[4], acc2[s]);
                acc2[s] = fmaf(b.y, wv2[5], acc2[s]);
                acc2[s] = fmaf(b.z, wv2[6], acc2[s]);
                acc2[s] = fmaf(b.w, wv2[7], acc2[s]);
            }
        }
    }
}

// 3x3x3 SAME submanifold conv (optionally concat second input, same cap).
template<int CIN1, int CIN2, int COUT, int SB, int HALVES, int S>
__global__ __launch_bounds__(256)
void gconv_cs(const float* __restrict__ inA, const float* __restrict__ inB,
              const float* __restrict__ w,
              const int* __restrict__ amap, const int* __restrict__ vlist,
              const int* __restrict__ cnt, int cap, float* __restrict__ out)
{
    constexpr int CTOT = CIN1 + CIN2;
    const int lane = threadIdx.x & 63;
    const int wid = threadIdx.x >> 6;
    const int base = (blockIdx.x * 4 + wid) * SB * HALVES;
    const int cntv = *cnt;
    if (base >= cntv) return;
    const int sidx = lane & 31;
    const int stream = (HALVES == 2) ? (lane >> 5) : 0;
    const bool slotlane = (sidx < SB) && (HALVES == 2 || lane < SB);
    const int myslot = base + stream * SB + sidx;
    int X = 0, Y = 0, Z = 0;
    const bool on = slotlane && (myslot < cntv);
    if (on) {
        const int v = vlist[myslot];
        X = v % S; const int r = v / S; Y = r % S; Z = r / S;
    }
    float acc[SB], acc2[SB];
#pragma unroll
    for (int s = 0; s < SB; ++s) { acc[s] = 0.f; acc2[s] = 0.f; }
#pragma unroll 1
    for (int t = 0; t < 27; ++t) {
        const int dz = t / 9 - 1, dy = (t / 3) % 3 - 1, dx = t % 3 - 1;
        int nsl = -1;
        if (on) {
            const int nz = Z + dz, ny = Y + dy, nx = X + dx;
            if ((unsigned)nz < (unsigned)S && (unsigned)ny < (unsigned)S &&
                (unsigned)nx < (unsigned)S)
                nsl = amap[(nz * S + ny) * S + nx];
        }
        const u64 mask = __ballot(nsl >= 0);
        if (mask == 0) continue;
        const u64 m2 = (HALVES == 2) ? (mask | (mask >> 32)) : mask;
        int ns0[SB], ns1[SB];
#pragma unroll
        for (int s = 0; s < SB; ++s) {
            const int a0 = __builtin_amdgcn_readlane(nsl, s);
            ns0[s] = (a0 < 0) ? cap : a0;
            if constexpr (HALVES == 2) {
                const int a1 = __builtin_amdgcn_readlane(nsl, 32 + s);
                ns1[s] = (a1 < 0) ? cap : a1;
            } else ns1[s] = 0;
        }
        const float* wT = w + (size_t)t * CTOT * COUT;
        ci_fma<CIN1, COUT, SB, HALVES>(inA, wT, m2, lane, ns0, ns1, acc, acc2);
        if constexpr (CIN2 > 0)
            ci_fma<CIN2, COUT, SB, HALVES>(inB, wT + CIN1 * COUT, m2, lane,
                                           ns0, ns1, acc, acc2);
    }
#pragma unroll
    for (int s = 0; s < SB; ++s) {
        if constexpr (HALVES == 2) {
            const int oslot = base + stream * SB + s;
            if (oslot < cntv) out[(size_t)oslot * COUT + sidx] = acc[s];
        } else {
            const int oslot = base + s;
            if (oslot < cntv) {
                out[(size_t)oslot * COUT + lane] = acc[s];
                if constexpr (COUT > 64)
                    if (lane < 32) out[(size_t)oslot * COUT + 64 + lane] = acc2[s];
            }
        }
    }
}

// 2x2x2 stride-2 down conv (coarse-driven; gathers fine children). HALVES=1.
template<int CIN, int COUT, int SB, int SC>
__global__ __launch_bounds__(256)
void dconv_cs(const float* __restrict__ in, const float* __restrict__ w,
              const int* __restrict__ amap_f, const int* __restrict__ vlist_c,
              const int* __restrict__ cnt_c, int capf, float* __restrict__ out)
{
    constexpr int SF = SC * 2;
    const int lane = threadIdx.x & 63;
    const int wid = threadIdx.x >> 6;
    const int base = (blockIdx.x * 4 + wid) * SB;
    const int cntv = *cnt_c;
    if (base >= cntv) return;
    const bool slotlane = lane < SB;
    const int myslot = base + lane;
    int X = 0, Y = 0, Z = 0;
    const bool on = slotlane && (myslot < cntv);
    if (on) {
        const int v = vlist_c[myslot];
        X = v % SC; const int r = v / SC; Y = r % SC; Z = r / SC;
    }
    float acc[SB], acc2[SB];
#pragma unroll
    for (int s = 0; s < SB; ++s) { acc[s] = 0.f; acc2[s] = 0.f; }
#pragma unroll 1
    for (int t = 0; t < 8; ++t) {
        int nsl = -1;
        if (on) {
            const int fz = 2 * Z + ((t >> 2) & 1);
            const int fy = 2 * Y + ((t >> 1) & 1);
            const int fx = 2 * X + (t & 1);
            nsl = amap_f[(fz * SF + fy) * SF + fx];
        }
        const u64 mask = __ballot(nsl >= 0);
        if (mask == 0) continue;
        int ns0[SB], ns1[SB];
#pragma unroll
        for (int s = 0; s < SB; ++s) {
            const int a0 = __builtin_amdgcn_readlane(nsl, s);
            ns0[s] = (a0 < 0) ? capf : a0;
            ns1[s] = 0;
        }
        const float* wT = w + (size_t)t * CIN * COUT;
        ci_fma<CIN, COUT, SB, 1>(in, wT, mask, lane, ns0, ns1, acc, acc2);
    }
#pragma unroll
    for (int s = 0; s < SB; ++s) {
        const int oslot = base + s;
        if (oslot < cntv) {
            out[(size_t)oslot * COUT + lane] = acc[s];
            if constexpr (COUT > 64)
                if (lane < 32) out[(size_t)oslot * COUT + 64 + lane] = acc2[s];
        }
    }
}

// Transpose conv 2x2x2 stride 2 (coarse-driven scatter; child r uses w[7-r]).
template<int CIN, int COUT, int SB, int HALVES, int SC>
__global__ __launch_bounds__(256)
void uconv_cs(const float* __restrict__ in, const float* __restrict__ w,
              const int* __restrict__ amap_f, const int* __restrict__ vlist_c,
              const int* __restrict__ cnt_c, int cap, float* __restrict__ out)
{
    constexpr int SF = SC * 2;
    const int lane = threadIdx.x & 63;
    const int wid = threadIdx.x >> 6;
    const int base = (blockIdx.x * 4 + wid) * SB * HALVES;
    const int cntv = *cnt_c;
    if (base >= cntv) return;
    const int sidx = lane & 31;
    const int stream = (HALVES == 2) ? (lane >> 5) : 0;
    const bool slotlane = (sidx < SB) && (HALVES == 2 || lane < SB);
    const int myslot = base + stream * SB + sidx;
    int X = 0, Y = 0, Z = 0;
    const bool on = slotlane && (myslot < cntv);
    if (on) {
        const int v = vlist_c[myslot];
        X = v % SC; const int r = v / SC; Y = r % SC; Z = r / SC;
    }
    int ns0[SB], ns1[SB];
#pragma unroll
    for (int s = 0; s < SB; ++s) {
        ns0[s] = min(base + s, cap);
        ns1[s] = (HALVES == 2) ? min(base + SB + s, cap) : 0;
    }
#pragma unroll 1
    for (int t = 0; t < 8; ++t) {
        int csl = -1;
        if (on) {
            const int fz = 2 * Z + ((t >> 2) & 1);
            const int fy = 2 * Y + ((t >> 1) & 1);
            const int fx = 2 * X + (t & 1);
            csl = amap_f[(fz * SF + fy) * SF + fx];
        }
        const u64 mask = __ballot(csl >= 0);
        if (mask == 0) continue;
        const u64 m2 = (HALVES == 2) ? (mask | (mask >> 32)) : mask;
        int cs0[SB], cs1[SB];
#pragma unroll
        for (int s = 0; s < SB; ++s) {
            cs0[s] = __builtin_amdgcn_readlane(csl, s);
            cs1[s] = (HALVES == 2) ? __builtin_amdgcn_readlane(csl, 32 + s) : 0;
        }
        float acc[SB], acc2[SB];
#pragma unroll
        for (int s = 0; s < SB; ++s) { acc[s] = 0.f; acc2[s] = 0.f; }
        const float* wT = w + (size_t)(7 - t) * CIN * COUT;
        ci_fma<CIN, COUT, SB, HALVES>(in, wT, m2, lane, ns0, ns1, acc, acc2);
#pragma unroll
        for (int s = 0; s < SB; ++s) {
            if constexpr (HALVES == 2) {
                const int b0 = (int)((mask >> s) & 1);
                const int b1 = (int)((mask >> (32 + s)) & 1);
                const int cssel = (lane < 32) ? cs0[s] : cs1[s];
                const bool vok = (lane < 32) ? (b0 != 0) : (b1 != 0);
                if (vok) out[(size_t)cssel * COUT + sidx] = acc[s];
            } else {
                if ((mask >> s) & 1)
                    out[(size_t)cs0[s] * COUT + lane] = acc[s];
            }
        }
    }
}

// First conv: dense 1-channel grid -> 32ch sparse (weights K$-resident).
template<int OSPLIT, int S>
__global__ __launch_bounds__(64 * OSPLIT)
void cin_k(const float* __restrict__ grid, const float* __restrict__ w,
           const int* __restrict__ vlist, const int* __restrict__ cnt,
           float* __restrict__ out)
{
    constexpr int OW = 32 / OSPLIT;
    const int wOff = __builtin_amdgcn_readfirstlane(threadIdx.x >> 6) * OW;
    const int slot = blockIdx.x * 64 + (threadIdx.x & 63);
    if (slot >= *cnt) return;
    const int v = vlist[slot];
    const int x = v % S;
    const int rem = v / S;
    const int y = rem % S;
    const int z = rem / S;
    float acc[OW];
#pragma unroll
    for (int c = 0; c < OW; ++c) acc[c] = 0.f;
#pragma unroll
    for (int t = 0; t < 27; ++t) {
        const int dz = t / 9 - 1, dy = (t / 3) % 3 - 1, dx = t % 3 - 1;
        const int nz = z + dz, ny = y + dy, nx = x + dx;
        if ((unsigned)nz >= (unsigned)S || (unsigned)ny >= (unsigned)S ||
            (unsigned)nx >= (unsigned)S) continue;
        const float val = grid[(nz * S + ny) * S + nx];
        const float* __restrict__ wp = w + t * 32 + wOff;
#pragma unroll
        for (int c = 0; c < OW; ++c) acc[c] = fmaf(val, wp[c], acc[c]);
    }
    float* __restrict__ op = out + (size_t)slot * 32 + wOff;
#pragma unroll
    for (int c = 0; c < OW; ++c) op[c] = acc[c];
}

// Elementwise bnrelu.
__global__ __launch_bounds__(256)
void act_k(const float* __restrict__ src, float* __restrict__ dst,
           const float* __restrict__ sc, const float* __restrict__ sh,
           const int* __restrict__ cnt, int C)
{
    const int f = (blockIdx.x * 256 + threadIdx.x) * 4;
    if (f >= (*cnt) * C) return;
    const int c0 = f % C;
    const float4 v = *reinterpret_cast<const float4*>(src + f);
    float4 o;
    o.x = fmaxf(fmaf(v.x, sc[c0 + 0], sh[c0 + 0]), 0.f);
    o.y = fmaxf(fmaf(v.y, sc[c0 + 1], sh[c0 + 1]), 0.f);
    o.z = fmaxf(fmaf(v.z, sc[c0 + 2], sh[c0 + 2]), 0.f);
    o.w = fmaxf(fmaf(v.w, sc[c0 + 3], sh[c0 + 3]), 0.f);
    *reinterpret_cast<float4*>(dst + f) = o;
}

// Final: bnrelu(y0, bnJ) then 32->3 linear per point.
__global__ __launch_bounds__(256)
void final_k(const int* __restrict__ coords, const float* __restrict__ y0,
             const int* __restrict__ amap0, const float* __restrict__ ssJ,
             const float* __restrict__ linW, const float* __restrict__ linb,
             int N, float* __restrict__ outp)
{
    const int n = blockIdx.x * blockDim.x + threadIdx.x;
    if (n >= N) return;
    const int i = coords[3 * n + 0];
    const int j = coords[3 * n + 1];
    const int k = coords[3 * n + 2];
    const int v = (i * NVOX + j) * NVOX + k;
    const int s = amap0[v];
    float a0 = linb[0], a1 = linb[1], a2 = linb[2];
    if (s >= 0) {
        const float* __restrict__ row = y0 + (size_t)s * 32;
#pragma unroll
        for (int c = 0; c < 32; ++c) {
            const float t = fmaxf(fmaf(row[c], ssJ[c], ssJ[32 + c]), 0.f);
            a0 = fmaf(t, linW[c * 3 + 0], a0);
            a1 = fmaf(t, linW[c * 3 + 1], a1);
            a2 = fmaf(t, linW[c * 3 + 2], a2);
        }
    }
    outp[3 * n + 0] = a0;
    outp[3 * n + 1] = a1;
    outp[3 * n + 2] = a2;
}

// Precompute per-channel scale/shift for all 10 BN layers.
__global__ void bn_prep(const float* __restrict__ A, const float* __restrict__ B,
                        const float* __restrict__ C, const float* __restrict__ D,
                        const float* __restrict__ E, const float* __restrict__ F,
                        const float* __restrict__ G, const float* __restrict__ H,
                        const float* __restrict__ I, const float* __restrict__ J,
                        float* __restrict__ ss)
{
    const float* bp[10] = {A, B, C, D, E, F, G, H, I, J};
    const int CH[10] = {32, 32, 64, 64, 96, 96, 128, 64, 64, 32};
    int idx = blockIdx.x * blockDim.x + threadIdx.x;
    if (idx >= 672) return;
    int l = 0, base = 0, off2 = 0;
    while (idx >= base + CH[l]) { base += CH[l]; off2 += 2 * CH[l]; ++l; }
    const int c = idx - base;
    const float* bn = bp[l];
    const int Cc = CH[l];
    const float g = bn[c], b = bn[Cc + c], mu = bn[2 * Cc + c], var = bn[3 * Cc + c];
    const float sc = g * rsqrtf(var + EPSB);
    ss[off2 + c] = sc;
    ss[off2 + Cc + c] = b - mu * sc;
}

__global__ __launch_bounds__(256)
void scatter_mark(const int* __restrict__ coords, const float* __restrict__ feats,
                  int N, float* __restrict__ grid, int* __restrict__ amap0)
{
    const int n = blockIdx.x * blockDim.x + threadIdx.x;
    if (n >= N) return;
    const int i = coords[3 * n + 0];
    const int j = coords[3 * n + 1];
    const int k = coords[3 * n + 2];
    const int v = (i * NVOX + j) * NVOX + k;
    atomicAdd(&grid[v], feats[n]);
    amap0[v] = -2;
}

template<int SC>
__global__ __launch_bounds__(256)
void flag_coarse(const int* __restrict__ amap_f, int* __restrict__ amap_c)
{
    constexpr int SF = SC * 2;
    const int v = blockIdx.x * blockDim.x + threadIdx.x;
    if (v >= SC * SC * SC) return;
    const int x = v % SC;
    const int rem = v / SC;
    const int y = rem % SC;
    const int z = rem / SC;
    bool any = false;
#pragma unroll
    for (int t = 0; t < 8; ++t) {
        const int fz = 2 * z + ((t >> 2) & 1);
        const int fy = 2 * y + ((t >> 1) & 1);
        const int fx = 2 * x + (t & 1);
        if (amap_f[(fz * SF + fy) * SF + fx] >= 0) any = true;
    }
    amap_c[v] = any ? -2 : -1;
}

// ---- deterministic raster-order compaction: count -> scan -> emit ----
__global__ __launch_bounds__(256)
void count_k(const int* __restrict__ flags, int V, int* __restrict__ counts)
{
    const int v = blockIdx.x * 256 + threadIdx.x;
    const bool act = (v < V) && (flags[v] == -2);
    const u64 m = __ballot(act);
    __shared__ int c[4];
    const int wid = threadIdx.x >> 6;
    if ((threadIdx.x & 63) == 0) c[wid] = __popcll(m);
    __syncthreads();
    if (threadIdx.x == 0) counts[blockIdx.x] = c[0] + c[1] + c[2] + c[3];
}

__global__ __launch_bounds__(1024)
void scan_k(int* __restrict__ counts, int nb, int* __restrict__ total)
{
    __shared__ int sums[1024];
    const int t = threadIdx.x;
    int v[4];
    int s = 0;
#pragma unroll
    for (int i = 0; i < 4; ++i) {
        const int idx = t * 4 + i;
        v[i] = (idx < nb) ? counts[idx] : 0;
        s += v[i];
    }
    sums[t] = s;
    __syncthreads();
    for (int d = 1; d < 1024; d <<= 1) {
        const int add = (t >= d) ? sums[t - d] : 0;
        __syncthreads();
        sums[t] += add;
        __syncthreads();
    }
    int base = (t > 0) ? sums[t - 1] : 0;
#pragma unroll
    for (int i = 0; i < 4; ++i) {
        const int idx = t * 4 + i;
        if (idx < nb) counts[idx] = base;
        base += v[i];
    }
    if (t == 1023) *total = sums[1023];
}

__global__ __launch_bounds__(256)
void emit_k(int* __restrict__ amap, int V, const int* __restrict__ offsets,
            int* __restrict__ vlist)
{
    const int v = blockIdx.x * 256 + threadIdx.x;
    const bool act = (v < V) && (amap[v] == -2);
    const u64 m = __ballot(act);
    __shared__ int wbase[4];
    const int wid = threadIdx.x >> 6;
    const int lane = threadIdx.x & 63;
    if (lane == 0) wbase[wid] = __popcll(m);
    __syncthreads();
    if (threadIdx.x == 0) {
        int s = 0;
#pragma unroll
        for (int i = 0; i < 4; ++i) { const int t = wbase[i]; wbase[i] = s; s += t; }
    }
    __syncthreads();
    if (act) {
        const int slot = offsets[blockIdx.x] + wbase[wid] +
                         __popcll(m & ((1ull << lane) - 1ull));
        amap[v] = slot;
        vlist[slot] = v;
    }
}

extern "C" void kernel_launch(void* const* d_in, const int* in_sizes, int n_in,
                              void* d_out, int out_size, void* d_ws, size_t ws_size,
                              hipStream_t stream) {
    const int*   coords = (const int*)d_in[0];
    const float* feats  = (const float*)d_in[1];
    const float* w_in   = (const float*)d_in[2];
    const float* w0a    = (const float*)d_in[3];
    const float* wdown0 = (const float*)d_in[4];
    const float* w1a    = (const float*)d_in[5];
    const float* wdown1 = (const float*)d_in[6];
    const float* w2     = (const float*)d_in[7];
    const float* wup1   = (const float*)d_in[8];
    const float* w1post = (const float*)d_in[9];
    const float* wup0   = (const float*)d_in[10];
    const float* w0post = (const float*)d_in[11];
    const float* linW = (const float*)d_in[22];
    const float* linb = (const float*)d_in[23];
    float* outp = (float*)d_out;

    const int N = in_sizes[1];            // 120000 points
    const int V0 = NVOX * NVOX * NVOX;
    const int V1 = 50 * 50 * 50;
    const int V2 = 25 * 25 * 25;
    const int cap0 = N;
    const int cap1 = 100000;
    const int cap2 = V2;

    char* ws = (char*)d_ws;
    size_t off = 0;
    auto alloc = [&](size_t bytes) -> void* {
        void* p = ws + off;
        off += (bytes + 255) & ~(size_t)255;
        return p;
    };
    int*   amap0  = (int*)alloc((size_t)V0 * 4);
    int*   vlist0 = (int*)alloc((size_t)cap0 * 4);
    int*   amap1  = (int*)alloc((size_t)V1 * 4);
    int*   vlist1 = (int*)alloc((size_t)cap1 * 4);
    int*   amap2  = (int*)alloc((size_t)V2 * 4);
    int*   vlist2 = (int*)alloc((size_t)cap2 * 4);
    int*   cnt    = (int*)alloc(3 * 4);
    int*   counts = (int*)alloc(4096 * 4);
    float* ss     = (float*)alloc(1344 * 4);
    float* grid   = (float*)alloc((size_t)V0 * 4);
    float* P1 = (float*)alloc((size_t)(cap0 + 1) * 32 * 4);  // x/actA -> u0/actI2
    float* P2 = (float*)alloc((size_t)(cap0 + 1) * 32 * 4);  // x0 -> y0
    float* P3 = (float*)alloc((size_t)(cap0 + 1) * 32 * 4);  // actB -> actI1
    float* Q1 = (float*)alloc((size_t)(cap1 + 1) * 64 * 4);  // d0/actC -> u1/actG2
    float* Q2 = (float*)alloc((size_t)(cap1 + 1) * 64 * 4);  // x1 -> y1/actH
    float* Q3 = (float*)alloc((size_t)(cap1 + 1) * 64 * 4);  // actD -> actG1
    float* R1 = (float*)alloc((size_t)(cap2 + 1) * 96 * 4);  // d1/actE
    float* R2 = (float*)alloc((size_t)(cap2 + 1) * 96 * 4);  // x2/actF
    if (off > ws_size) return;

    const int B = 256;
    const int gN  = (N + B - 1) / B;
    const int nb0 = (V0 + B - 1) / B;
    const int nb1 = (V1 + B - 1) / B;
    const int nb2 = (V2 + B - 1) / B;
    const int gA32 = (cap0 * 32 / 4 + 255) / 256;
    const int gA64 = (cap1 * 64 / 4 + 255) / 256;
    const int gA96 = (cap2 * 96 / 4 + 255) / 256;
    // conv grids (4 waves/block): slots per block = SB(8) * HALVES * 4
    const int g_l0 = (cap0 + 63) / 64;   // HALVES=2 -> 64 slots/block
    const int g_l1 = (cap1 + 31) / 32;   // HALVES=1
    const int g_l2 = (cap2 + 31) / 32;
    const int g_u0 = (cap1 + 63) / 64;   // HALVES=2
    const int g_ci = (cap0 + 63) / 64;

    // ---- build phase ----
    hipMemsetAsync(amap0, 0xFF, (size_t)V0 * 4, stream);
    hipMemsetAsync(grid, 0, (size_t)V0 * 4, stream);
    // zero rows at slot index cap for gather-input buffers
    hipMemsetAsync(P1 + (size_t)cap0 * 32, 0, 32 * 4, stream);
    hipMemsetAsync(P3 + (size_t)cap0 * 32, 0, 32 * 4, stream);
    hipMemsetAsync(Q1 + (size_t)cap1 * 64, 0, 64 * 4, stream);
    hipMemsetAsync(Q3 + (size_t)cap1 * 64, 0, 64 * 4, stream);
    hipMemsetAsync(R1 + (size_t)cap2 * 96, 0, 96 * 4, stream);
    hipMemsetAsync(R2 + (size_t)cap2 * 96, 0, 96 * 4, stream);
    bn_prep<<<3, 256, 0, stream>>>((const float*)d_in[12], (const float*)d_in[13],
                                   (const float*)d_in[14], (const float*)d_in[15],
                                   (const float*)d_in[16], (const float*)d_in[17],
                                   (const float*)d_in[18], (const float*)d_in[19],
                                   (const float*)d_in[20], (const float*)d_in[21], ss);
    scatter_mark<<<gN, B, 0, stream>>>(coords, feats, N, grid, amap0);
    count_k<<<nb0, B, 0, stream>>>(amap0, V0, counts);
    scan_k<<<1, 1024, 0, stream>>>(counts, nb0, cnt + 0);
    emit_k<<<nb0, B, 0, stream>>>(amap0, V0, counts, vlist0);
    flag_coarse<50><<<nb1, B, 0, stream>>>(amap0, amap1);
    count_k<<<nb1, B, 0, stream>>>(amap1, V1, counts);
    scan_k<<<1, 1024, 0, stream>>>(counts, nb1, cnt + 1);
    emit_k<<<nb1, B, 0, stream>>>(amap1, V1, counts, vlist1);
    flag_coarse<25><<<nb2, B, 0, stream>>>(amap1, amap2);
    count_k<<<nb2, B, 0, stream>>>(amap2, V2, counts);
    scan_k<<<1, 1024, 0, stream>>>(counts, nb2, cnt + 2);
    emit_k<<<nb2, B, 0, stream>>>(amap2, V2, counts, vlist2);

    // ---- network ----
    cin_k<2, 100><<<g_ci, 128, 0, stream>>>(grid, w_in, vlist0, cnt + 0, P1);
    act_k<<<gA32, 256, 0, stream>>>(P1, P1, ss + 0, ss + 32, cnt + 0, 32);
    gconv_cs<32, 0, 32, 8, 2, 100><<<g_l0, 256, 0, stream>>>(
        P1, nullptr, w0a, amap0, vlist0, cnt + 0, cap0, P2);
    act_k<<<gA32, 256, 0, stream>>>(P2, P3, ss + 64, ss + 96, cnt + 0, 32);
    dconv_cs<32, 64, 8, 50><<<g_l1, 256, 0, stream>>>(
        P3, wdown0, amap0, vlist1, cnt + 1, cap0, Q1);
    act_k<<<gA64, 256, 0, stream>>>(Q1, Q1, ss + 128, ss + 192, cnt + 1, 64);
    gconv_cs<64, 0, 64, 8, 1, 50><<<g_l1, 256, 0, stream>>>(
        Q1, nullptr, w1a, amap1, vlist1, cnt + 1, cap1, Q2);
    act_k<<<gA64, 256, 0, stream>>>(Q2, Q3, ss + 256, ss + 320, cnt + 1, 64);
    dconv_cs<64, 96, 8, 25><<<g_l2, 256, 0, stream>>>(
        Q3, wdown1, amap1, vlist2, cnt + 2, cap1, R1);
    act_k<<<gA96, 256, 0, stream>>>(R1, R1, ss + 384, ss + 480, cnt + 2, 96);
    gconv_cs<96, 0, 96, 8, 1, 25><<<g_l2, 256, 0, stream>>>(
        R1, nullptr, w2, amap2, vlist2, cnt + 2, cap2, R2);
    act_k<<<gA96, 256, 0, stream>>>(R2, R2, ss + 576, ss + 672, cnt + 2, 96);
    uconv_cs<96, 64, 8, 1, 25><<<g_l2, 256, 0, stream>>>(
        R2, wup1, amap1, vlist2, cnt + 2, cap2, Q1);
    act_k<<<gA64, 256, 0, stream>>>(Q2, Q3, ss + 768, ss + 896, cnt + 1, 64);
    act_k<<<gA64, 256, 0, stream>>>(Q1, Q1, ss + 768 + 64, ss + 896 + 64, cnt + 1, 64);
    gconv_cs<64, 64, 64, 8, 1, 50><<<g_l1, 256, 0, stream>>>(
        Q3, Q1, w1post, amap1, vlist1, cnt + 1, cap1, Q2);
    act_k<<<gA64, 256, 0, stream>>>(Q2, Q2, ss + 1024, ss + 1088, cnt + 1, 64);
    uconv_cs<64, 32, 8, 2, 50><<<g_u0, 256, 0, stream>>>(
        Q2, wup0, amap0, vlist1, cnt + 1, cap1, P1);
    act_k<<<gA32, 256, 0, stream>>>(P2, P3, ss + 1152, ss + 1216, cnt + 0, 32);
    act_k<<<gA32, 256, 0, stream>>>(P1, P1, ss + 1152 + 32, ss + 1216 + 32, cnt + 0, 32);
    gconv_cs<32, 32, 32, 8, 2, 100><<<g_l0, 256, 0, stream>>>(
        P3, P1, w0post, amap0, vlist0, cnt + 0, cap0, P2);
    final_k<<<gN, B, 0, stream>>>(coords, P2, amap0, ss + 1280, linW, linb, N, outp);
}

// Round 5
// 2327.730 us; speedup vs baseline: 1.2366x; 1.2366x over previous
//
#include <hip/hip_runtime.h>

// ---------------------------------------------------------------------------
// Sparse 3D U-Net forward (MI355X / gfx950), f32.
// Thread = slot (lane), waves split output channels (8 couts/wave, 32/block),
// gridDim.y splits COUT into 32-wide blocks. Weights LDS-staged per tap
// (double-buffered, prefetched: load->compute->ds_write->sync). Raster-ordered
// slots via deterministic prefix-scan compaction.
// ---------------------------------------------------------------------------

#define NVOX 100
#define EPSB 1e-4f
typedef unsigned long long u64;
#define DEVFN __device__ __forceinline__

// acc[0..7] += row[ci] * wl[ci*32 + {0..7}]  (wl pre-offset by wave's 8 couts)
template<int CIN>
DEVFN void dorow8(const float* __restrict__ row, const float* __restrict__ wl,
                  float (&acc)[8])
{
#pragma unroll 4
    for (int c0 = 0; c0 < CIN; c0 += 4) {
        const float4 a = *reinterpret_cast<const float4*>(row + c0);
        const float av[4] = {a.x, a.y, a.z, a.w};
#pragma unroll
        for (int j = 0; j < 4; ++j) {
            const float4 w0 = *reinterpret_cast<const float4*>(wl + (c0 + j) * 32);
            const float4 w1 = *reinterpret_cast<const float4*>(wl + (c0 + j) * 32 + 4);
            acc[0] = fmaf(av[j], w0.x, acc[0]);
            acc[1] = fmaf(av[j], w0.y, acc[1]);
            acc[2] = fmaf(av[j], w0.z, acc[2]);
            acc[3] = fmaf(av[j], w0.w, acc[3]);
            acc[4] = fmaf(av[j], w1.x, acc[4]);
            acc[5] = fmaf(av[j], w1.y, acc[5]);
            acc[6] = fmaf(av[j], w1.z, acc[6]);
            acc[7] = fmaf(av[j], w1.w, acc[7]);
        }
    }
}

// 3x3x3 SAME submanifold conv (optional concat second input).
// grid = (ceil(cap/64), COUT/32); block = 256 (4 waves; wave w -> couts w*8..).
template<int CIN1, int CIN2, int COUT, int S>
__global__ __launch_bounds__(256)
void gconv_w(const float* __restrict__ inA, const float* __restrict__ inB,
             const float* __restrict__ w,
             const int* __restrict__ amap, const int* __restrict__ vlist,
             const int* __restrict__ cnt, float* __restrict__ out)
{
    constexpr int CTOT = CIN1 + CIN2;
    constexpr int F = CTOT * 32;       // LDS slice floats
    constexpr int PER = F / 1024;      // float4 per thread per stage
    __shared__ float lw[2][F];
    const int tid = threadIdx.x;
    const int lane = tid & 63;
    const int wid = tid >> 6;
    const int cntv = *cnt;
    if (blockIdx.x * 64 >= cntv) return;
    const int slot = blockIdx.x * 64 + lane;
    const int cg32 = blockIdx.y * 32;
    const bool on = slot < cntv;
    int X = 0, Y = 0, Z = 0;
    if (on) { const int v = vlist[slot]; X = v % S; const int r = v / S; Y = r % S; Z = r / S; }
    float acc[8];
#pragma unroll
    for (int q = 0; q < 8; ++q) acc[q] = 0.f;
    float4 st[PER];
    // prologue: stage tap 0
#pragma unroll
    for (int i = 0; i < PER; ++i) {
        const int idx4 = (i * 256 + tid) * 4;
        st[i] = *reinterpret_cast<const float4*>(w + (idx4 >> 5) * COUT + cg32 + (idx4 & 31));
    }
#pragma unroll
    for (int i = 0; i < PER; ++i)
        *reinterpret_cast<float4*>(&lw[0][(i * 256 + tid) * 4]) = st[i];
    __syncthreads();
#pragma unroll 1
    for (int t = 0; t < 27; ++t) {
        if (t + 1 < 27) {  // issue next tap's weight loads (in flight during compute)
            const float* __restrict__ src = w + (size_t)(t + 1) * CTOT * COUT;
#pragma unroll
            for (int i = 0; i < PER; ++i) {
                const int idx4 = (i * 256 + tid) * 4;
                st[i] = *reinterpret_cast<const float4*>(src + (idx4 >> 5) * COUT + cg32 + (idx4 & 31));
            }
        }
        int ns = -1;
        if (on) {
            const int dz = t / 9 - 1, dy = (t / 3) % 3 - 1, dx = t % 3 - 1;
            const int nz = Z + dz, ny = Y + dy, nx = X + dx;
            if ((unsigned)nz < (unsigned)S && (unsigned)ny < (unsigned)S &&
                (unsigned)nx < (unsigned)S)
                ns = amap[(nz * S + ny) * S + nx];
        }
        if (ns >= 0) {
            const float* __restrict__ wl = &lw[t & 1][wid * 8];
            dorow8<CIN1>(inA + (size_t)ns * CIN1, wl, acc);
            if constexpr (CIN2 > 0)
                dorow8<CIN2>(inB + (size_t)ns * CIN2, wl + CIN1 * 32, acc);
        }
        if (t + 1 < 27) {
#pragma unroll
            for (int i = 0; i < PER; ++i)
                *reinterpret_cast<float4*>(&lw[(t + 1) & 1][(i * 256 + tid) * 4]) = st[i];
        }
        __syncthreads();
    }
    if (on) {
        float* __restrict__ op = out + (size_t)slot * COUT + cg32 + wid * 8;
        *reinterpret_cast<float4*>(op) = make_float4(acc[0], acc[1], acc[2], acc[3]);
        *reinterpret_cast<float4*>(op + 4) = make_float4(acc[4], acc[5], acc[6], acc[7]);
    }
}

// 2x2x2 stride-2 down conv, coarse-driven. grid = (ceil(capc/64), COUT/32).
template<int CIN, int COUT, int SC>
__global__ __launch_bounds__(256)
void dconv_w(const float* __restrict__ in, const float* __restrict__ w,
             const int* __restrict__ amap_f, const int* __restrict__ vlist_c,
             const int* __restrict__ cnt_c, float* __restrict__ out)
{
    constexpr int SF = SC * 2;
    constexpr int F = CIN * 32;
    constexpr int PER = F / 1024;
    __shared__ float lw[2][F];
    const int tid = threadIdx.x;
    const int lane = tid & 63;
    const int wid = tid >> 6;
    const int cntv = *cnt_c;
    if (blockIdx.x * 64 >= cntv) return;
    const int slot = blockIdx.x * 64 + lane;
    const int cg32 = blockIdx.y * 32;
    const bool on = slot < cntv;
    int X = 0, Y = 0, Z = 0;
    if (on) { const int v = vlist_c[slot]; X = v % SC; const int r = v / SC; Y = r % SC; Z = r / SC; }
    float acc[8];
#pragma unroll
    for (int q = 0; q < 8; ++q) acc[q] = 0.f;
    float4 st[PER];
#pragma unroll
    for (int i = 0; i < PER; ++i) {
        const int idx4 = (i * 256 + tid) * 4;
        st[i] = *reinterpret_cast<const float4*>(w + (idx4 >> 5) * COUT + cg32 + (idx4 & 31));
    }
#pragma unroll
    for (int i = 0; i < PER; ++i)
        *reinterpret_cast<float4*>(&lw[0][(i * 256 + tid) * 4]) = st[i];
    __syncthreads();
#pragma unroll 1
    for (int t = 0; t < 8; ++t) {
        if (t + 1 < 8) {
            const float* __restrict__ src = w + (size_t)(t + 1) * CIN * COUT;
#pragma unroll
            for (int i = 0; i < PER; ++i) {
                const int idx4 = (i * 256 + tid) * 4;
                st[i] = *reinterpret_cast<const float4*>(src + (idx4 >> 5) * COUT + cg32 + (idx4 & 31));
            }
        }
        int ns = -1;
        if (on) {
            const int fz = 2 * Z + ((t >> 2) & 1);
            const int fy = 2 * Y + ((t >> 1) & 1);
            const int fx = 2 * X + (t & 1);
            ns = amap_f[(fz * SF + fy) * SF + fx];
        }
        if (ns >= 0)
            dorow8<CIN>(in + (size_t)ns * CIN, &lw[t & 1][wid * 8], acc);
        if (t + 1 < 8) {
#pragma unroll
            for (int i = 0; i < PER; ++i)
                *reinterpret_cast<float4*>(&lw[(t + 1) & 1][(i * 256 + tid) * 4]) = st[i];
        }
        __syncthreads();
    }
    if (on) {
        float* __restrict__ op = out + (size_t)slot * COUT + cg32 + wid * 8;
        *reinterpret_cast<float4*>(op) = make_float4(acc[0], acc[1], acc[2], acc[3]);
        *reinterpret_cast<float4*>(op + 4) = make_float4(acc[4], acc[5], acc[6], acc[7]);
    }
}

// Transpose conv 2x2x2 stride 2, coarse-driven scatter; child t uses w[7-t].
template<int CIN, int COUT, int SC>
__global__ __launch_bounds__(256)
void uconv_w(const float* __restrict__ in, const float* __restrict__ w,
             const int* __restrict__ amap_f, const int* __restrict__ vlist_c,
             const int* __restrict__ cnt_c, float* __restrict__ out)
{
    constexpr int SF = SC * 2;
    constexpr int F = CIN * 32;
    constexpr int PER = F / 1024;
    __shared__ float lw[2][F];
    const int tid = threadIdx.x;
    const int lane = tid & 63;
    const int wid = tid >> 6;
    const int cntv = *cnt_c;
    if (blockIdx.x * 64 >= cntv) return;
    const int slot = blockIdx.x * 64 + lane;
    const int cg32 = blockIdx.y * 32;
    const bool on = slot < cntv;
    int X = 0, Y = 0, Z = 0;
    if (on) { const int v = vlist_c[slot]; X = v % SC; const int r = v / SC; Y = r % SC; Z = r / SC; }
    float4 st[PER];
    // prologue: stage weight tap 7 (used by child t=0)
#pragma unroll
    for (int i = 0; i < PER; ++i) {
        const int idx4 = (i * 256 + tid) * 4;
        st[i] = *reinterpret_cast<const float4*>(w + (size_t)7 * CIN * COUT +
                                                 (idx4 >> 5) * COUT + cg32 + (idx4 & 31));
    }
#pragma unroll
    for (int i = 0; i < PER; ++i)
        *reinterpret_cast<float4*>(&lw[0][(i * 256 + tid) * 4]) = st[i];
    __syncthreads();
#pragma unroll 1
    for (int t = 0; t < 8; ++t) {
        if (t + 1 < 8) {  // next child uses weight tap 7-(t+1) = 6-t
            const float* __restrict__ src = w + (size_t)(6 - t) * CIN * COUT;
#pragma unroll
            for (int i = 0; i < PER; ++i) {
                const int idx4 = (i * 256 + tid) * 4;
                st[i] = *reinterpret_cast<const float4*>(src + (idx4 >> 5) * COUT + cg32 + (idx4 & 31));
            }
        }
        int cs = -1;
        if (on) {
            const int fz = 2 * Z + ((t >> 2) & 1);
            const int fy = 2 * Y + ((t >> 1) & 1);
            const int fx = 2 * X + (t & 1);
            cs = amap_f[(fz * SF + fy) * SF + fx];
        }
        if (cs >= 0) {
            float acc[8];
#pragma unroll
            for (int q = 0; q < 8; ++q) acc[q] = 0.f;
            dorow8<CIN>(in + (size_t)slot * CIN, &lw[t & 1][wid * 8], acc);
            float* __restrict__ op = out + (size_t)cs * COUT + cg32 + wid * 8;
            *reinterpret_cast<float4*>(op) = make_float4(acc[0], acc[1], acc[2], acc[3]);
            *reinterpret_cast<float4*>(op + 4) = make_float4(acc[4], acc[5], acc[6], acc[7]);
        }
        if (t + 1 < 8) {
#pragma unroll
            for (int i = 0; i < PER; ++i)
                *reinterpret_cast<float4*>(&lw[(t + 1) & 1][(i * 256 + tid) * 4]) = st[i];
        }
        __syncthreads();
    }
}

// First conv: dense 1-channel grid -> 32ch sparse (weights tiny, K$-resident).
template<int OSPLIT, int S>
__global__ __launch_bounds__(64 * OSPLIT)
void cin_k(const float* __restrict__ grid, const float* __restrict__ w,
           const int* __restrict__ vlist, const int* __restrict__ cnt,
           float* __restrict__ out)
{
    constexpr int OW = 32 / OSPLIT;
    const int wOff = __builtin_amdgcn_readfirstlane(threadIdx.x >> 6) * OW;
    const int slot = blockIdx.x * 64 + (threadIdx.x & 63);
    if (slot >= *cnt) return;
    const int v = vlist[slot];
    const int x = v % S;
    const int rem = v / S;
    const int y = rem % S;
    const int z = rem / S;
    float acc[OW];
#pragma unroll
    for (int c = 0; c < OW; ++c) acc[c] = 0.f;
#pragma unroll
    for (int t = 0; t < 27; ++t) {
        const int dz = t / 9 - 1, dy = (t / 3) % 3 - 1, dx = t % 3 - 1;
        const int nz = z + dz, ny = y + dy, nx = x + dx;
        if ((unsigned)nz >= (unsigned)S || (unsigned)ny >= (unsigned)S ||
            (unsigned)nx >= (unsigned)S) continue;
        const float val = grid[(nz * S + ny) * S + nx];
        const float* __restrict__ wp = w + t * 32 + wOff;
#pragma unroll
        for (int c = 0; c < OW; ++c) acc[c] = fmaf(val, wp[c], acc[c]);
    }
    float* __restrict__ op = out + (size_t)slot * 32 + wOff;
#pragma unroll
    for (int c = 0; c < OW; ++c) op[c] = acc[c];
}

// Elementwise bnrelu.
__global__ __launch_bounds__(256)
void act_k(const float* __restrict__ src, float* __restrict__ dst,
           const float* __restrict__ sc, const float* __restrict__ sh,
           const int* __restrict__ cnt, int C)
{
    const int f = (blockIdx.x * 256 + threadIdx.x) * 4;
    if (f >= (*cnt) * C) return;
    const int c0 = f % C;
    const float4 v = *reinterpret_cast<const float4*>(src + f);
    float4 o;
    o.x = fmaxf(fmaf(v.x, sc[c0 + 0], sh[c0 + 0]), 0.f);
    o.y = fmaxf(fmaf(v.y, sc[c0 + 1], sh[c0 + 1]), 0.f);
    o.z = fmaxf(fmaf(v.z, sc[c0 + 2], sh[c0 + 2]), 0.f);
    o.w = fmaxf(fmaf(v.w, sc[c0 + 3], sh[c0 + 3]), 0.f);
    *reinterpret_cast<float4*>(dst + f) = o;
}

// Final: bnrelu(y0, bnJ) then 32->3 linear per point.
__global__ __launch_bounds__(256)
void final_k(const int* __restrict__ coords, const float* __restrict__ y0,
             const int* __restrict__ amap0, const float* __restrict__ ssJ,
             const float* __restrict__ linW, const float* __restrict__ linb,
             int N, float* __restrict__ outp)
{
    const int n = blockIdx.x * blockDim.x + threadIdx.x;
    if (n >= N) return;
    const int i = coords[3 * n + 0];
    const int j = coords[3 * n + 1];
    const int k = coords[3 * n + 2];
    const int v = (i * NVOX + j) * NVOX + k;
    const int s = amap0[v];
    float a0 = linb[0], a1 = linb[1], a2 = linb[2];
    if (s >= 0) {
        const float* __restrict__ row = y0 + (size_t)s * 32;
#pragma unroll
        for (int c = 0; c < 32; ++c) {
            const float t = fmaxf(fmaf(row[c], ssJ[c], ssJ[32 + c]), 0.f);
            a0 = fmaf(t, linW[c * 3 + 0], a0);
            a1 = fmaf(t, linW[c * 3 + 1], a1);
            a2 = fmaf(t, linW[c * 3 + 2], a2);
        }
    }
    outp[3 * n + 0] = a0;
    outp[3 * n + 1] = a1;
    outp[3 * n + 2] = a2;
}

// Precompute per-channel scale/shift for all 10 BN layers.
__global__ void bn_prep(const float* __restrict__ A, const float* __restrict__ B,
                        const float* __restrict__ C, const float* __restrict__ D,
                        const float* __restrict__ E, const float* __restrict__ F,
                        const float* __restrict__ G, const float* __restrict__ H,
                        const float* __restrict__ I, const float* __restrict__ J,
                        float* __restrict__ ss)
{
    const float* bp[10] = {A, B, C, D, E, F, G, H, I, J};
    const int CH[10] = {32, 32, 64, 64, 96, 96, 128, 64, 64, 32};
    int idx = blockIdx.x * blockDim.x + threadIdx.x;
    if (idx >= 672) return;
    int l = 0, base = 0, off2 = 0;
    while (idx >= base + CH[l]) { base += CH[l]; off2 += 2 * CH[l]; ++l; }
    const int c = idx - base;
    const float* bn = bp[l];
    const int Cc = CH[l];
    const float g = bn[c], b = bn[Cc + c], mu = bn[2 * Cc + c], var = bn[3 * Cc + c];
    const float sc = g * rsqrtf(var + EPSB);
    ss[off2 + c] = sc;
    ss[off2 + Cc + c] = b - mu * sc;
}

__global__ __launch_bounds__(256)
void scatter_mark(const int* __restrict__ coords, const float* __restrict__ feats,
                  int N, float* __restrict__ grid, int* __restrict__ amap0)
{
    const int n = blockIdx.x * blockDim.x + threadIdx.x;
    if (n >= N) return;
    const int i = coords[3 * n + 0];
    const int j = coords[3 * n + 1];
    const int k = coords[3 * n + 2];
    const int v = (i * NVOX + j) * NVOX + k;
    atomicAdd(&grid[v], feats[n]);
    amap0[v] = -2;
}

template<int SC>
__global__ __launch_bounds__(256)
void flag_coarse(const int* __restrict__ amap_f, int* __restrict__ amap_c)
{
    constexpr int SF = SC * 2;
    const int v = blockIdx.x * blockDim.x + threadIdx.x;
    if (v >= SC * SC * SC) return;
    const int x = v % SC;
    const int rem = v / SC;
    const int y = rem % SC;
    const int z = rem / SC;
    bool any = false;
#pragma unroll
    for (int t = 0; t < 8; ++t) {
        const int fz = 2 * z + ((t >> 2) & 1);
        const int fy = 2 * y + ((t >> 1) & 1);
        const int fx = 2 * x + (t & 1);
        if (amap_f[(fz * SF + fy) * SF + fx] >= 0) any = true;
    }
    amap_c[v] = any ? -2 : -1;
}

// ---- deterministic raster-order compaction: count -> scan -> emit ----
__global__ __launch_bounds__(256)
void count_k(const int* __restrict__ flags, int V, int* __restrict__ counts)
{
    const int v = blockIdx.x * 256 + threadIdx.x;
    const bool act = (v < V) && (flags[v] == -2);
    const u64 m = __ballot(act);
    __shared__ int c[4];
    const int wid = threadIdx.x >> 6;
    if ((threadIdx.x & 63) == 0) c[wid] = __popcll(m);
    __syncthreads();
    if (threadIdx.x == 0) counts[blockIdx.x] = c[0] + c[1] + c[2] + c[3];
}

__global__ __launch_bounds__(1024)
void scan_k(int* __restrict__ counts, int nb, int* __restrict__ total)
{
    __shared__ int sums[1024];
    const int t = threadIdx.x;
    int v[4];
    int s = 0;
#pragma unroll
    for (int i = 0; i < 4; ++i) {
        const int idx = t * 4 + i;
        v[i] = (idx < nb) ? counts[idx] : 0;
        s += v[i];
    }
    sums[t] = s;
    __syncthreads();
    for (int d = 1; d < 1024; d <<= 1) {
        const int add = (t >= d) ? sums[t - d] : 0;
        __syncthreads();
        sums[t] += add;
        __syncthreads();
    }
    int base = (t > 0) ? sums[t - 1] : 0;
#pragma unroll
    for (int i = 0; i < 4; ++i) {
        const int idx = t * 4 + i;
        if (idx < nb) counts[idx] = base;
        base += v[i];
    }
    if (t == 1023) *total = sums[1023];
}

__global__ __launch_bounds__(256)
void emit_k(int* __restrict__ amap, int V, const int* __restrict__ offsets,
            int* __restrict__ vlist)
{
    const int v = blockIdx.x * 256 + threadIdx.x;
    const bool act = (v < V) && (amap[v] == -2);
    const u64 m = __ballot(act);
    __shared__ int wbase[4];
    const int wid = threadIdx.x >> 6;
    const int lane = threadIdx.x & 63;
    if (lane == 0) wbase[wid] = __popcll(m);
    __syncthreads();
    if (threadIdx.x == 0) {
        int s = 0;
#pragma unroll
        for (int i = 0; i < 4; ++i) { const int t = wbase[i]; wbase[i] = s; s += t; }
    }
    __syncthreads();
    if (act) {
        const int slot = offsets[blockIdx.x] + wbase[wid] +
                         __popcll(m & ((1ull << lane) - 1ull));
        amap[v] = slot;
        vlist[slot] = v;
    }
}

extern "C" void kernel_launch(void* const* d_in, const int* in_sizes, int n_in,
                              void* d_out, int out_size, void* d_ws, size_t ws_size,
                              hipStream_t stream) {
    const int*   coords = (const int*)d_in[0];
    const float* feats  = (const float*)d_in[1];
    const float* w_in   = (const float*)d_in[2];
    const float* w0a    = (const float*)d_in[3];
    const float* wdown0 = (const float*)d_in[4];
    const float* w1a    = (const float*)d_in[5];
    const float* wdown1 = (const float*)d_in[6];
    const float* w2     = (const float*)d_in[7];
    const float* wup1   = (const float*)d_in[8];
    const float* w1post = (const float*)d_in[9];
    const float* wup0   = (const float*)d_in[10];
    const float* w0post = (const float*)d_in[11];
    const float* linW = (const float*)d_in[22];
    const float* linb = (const float*)d_in[23];
    float* outp = (float*)d_out;

    const int N = in_sizes[1];            // 120000 points
    const int V0 = NVOX * NVOX * NVOX;
    const int V1 = 50 * 50 * 50;
    const int V2 = 25 * 25 * 25;
    const int cap0 = N;
    const int cap1 = 100000;
    const int cap2 = V2;

    char* ws = (char*)d_ws;
    size_t off = 0;
    auto alloc = [&](size_t bytes) -> void* {
        void* p = ws + off;
        off += (bytes + 255) & ~(size_t)255;
        return p;
    };
    int*   amap0  = (int*)alloc((size_t)V0 * 4);
    int*   vlist0 = (int*)alloc((size_t)cap0 * 4);
    int*   amap1  = (int*)alloc((size_t)V1 * 4);
    int*   vlist1 = (int*)alloc((size_t)cap1 * 4);
    int*   amap2  = (int*)alloc((size_t)V2 * 4);
    int*   vlist2 = (int*)alloc((size_t)cap2 * 4);
    int*   cnt    = (int*)alloc(3 * 4);
    int*   counts = (int*)alloc(4096 * 4);
    float* ss     = (float*)alloc(1344 * 4);
    float* grid   = (float*)alloc((size_t)V0 * 4);
    float* P1 = (float*)alloc((size_t)cap0 * 32 * 4);  // x/actA -> u0/actI2
    float* P2 = (float*)alloc((size_t)cap0 * 32 * 4);  // x0 -> y0
    float* P3 = (float*)alloc((size_t)cap0 * 32 * 4);  // actB -> actI1
    float* Q1 = (float*)alloc((size_t)cap1 * 64 * 4);  // d0/actC -> u1/actG2
    float* Q2 = (float*)alloc((size_t)cap1 * 64 * 4);  // x1 -> y1/actH
    float* Q3 = (float*)alloc((size_t)cap1 * 64 * 4);  // actD -> actG1
    float* R1 = (float*)alloc((size_t)cap2 * 96 * 4);  // d1/actE
    float* R2 = (float*)alloc((size_t)cap2 * 96 * 4);  // x2/actF
    if (off > ws_size) return;

    const int B = 256;
    const int gN  = (N + B - 1) / B;
    const int nb0 = (V0 + B - 1) / B;
    const int nb1 = (V1 + B - 1) / B;
    const int nb2 = (V2 + B - 1) / B;
    const int gA32 = (cap0 * 32 / 4 + 255) / 256;
    const int gA64 = (cap1 * 64 / 4 + 255) / 256;
    const int gA96 = (cap2 * 96 / 4 + 255) / 256;
    const int sb0 = (cap0 + 63) / 64;   // 1875 slot-blocks at L0
    const int sb1 = (cap1 + 63) / 64;   // 1563 at L1
    const int sb2 = (cap2 + 63) / 64;   // 245 at L2

    // ---- build phase ----
    hipMemsetAsync(amap0, 0xFF, (size_t)V0 * 4, stream);
    hipMemsetAsync(grid, 0, (size_t)V0 * 4, stream);
    bn_prep<<<3, 256, 0, stream>>>((const float*)d_in[12], (const float*)d_in[13],
                                   (const float*)d_in[14], (const float*)d_in[15],
                                   (const float*)d_in[16], (const float*)d_in[17],
                                   (const float*)d_in[18], (const float*)d_in[19],
                                   (const float*)d_in[20], (const float*)d_in[21], ss);
    scatter_mark<<<gN, B, 0, stream>>>(coords, feats, N, grid, amap0);
    count_k<<<nb0, B, 0, stream>>>(amap0, V0, counts);
    scan_k<<<1, 1024, 0, stream>>>(counts, nb0, cnt + 0);
    emit_k<<<nb0, B, 0, stream>>>(amap0, V0, counts, vlist0);
    flag_coarse<50><<<nb1, B, 0, stream>>>(amap0, amap1);
    count_k<<<nb1, B, 0, stream>>>(amap1, V1, counts);
    scan_k<<<1, 1024, 0, stream>>>(counts, nb1, cnt + 1);
    emit_k<<<nb1, B, 0, stream>>>(amap1, V1, counts, vlist1);
    flag_coarse<25><<<nb2, B, 0, stream>>>(amap1, amap2);
    count_k<<<nb2, B, 0, stream>>>(amap2, V2, counts);
    scan_k<<<1, 1024, 0, stream>>>(counts, nb2, cnt + 2);
    emit_k<<<nb2, B, 0, stream>>>(amap2, V2, counts, vlist2);

    // ---- network ----
    cin_k<2, 100><<<sb0, 128, 0, stream>>>(grid, w_in, vlist0, cnt + 0, P1);
    act_k<<<gA32, 256, 0, stream>>>(P1, P1, ss + 0, ss + 32, cnt + 0, 32);
    gconv_w<32, 0, 32, 100><<<dim3(sb0, 1), 256, 0, stream>>>(
        P1, nullptr, w0a, amap0, vlist0, cnt + 0, P2);
    act_k<<<gA32, 256, 0, stream>>>(P2, P3, ss + 64, ss + 96, cnt + 0, 32);
    dconv_w<32, 64, 50><<<dim3(sb1, 2), 256, 0, stream>>>(
        P3, wdown0, amap0, vlist1, cnt + 1, Q1);
    act_k<<<gA64, 256, 0, stream>>>(Q1, Q1, ss + 128, ss + 192, cnt + 1, 64);
    gconv_w<64, 0, 64, 50><<<dim3(sb1, 2), 256, 0, stream>>>(
        Q1, nullptr, w1a, amap1, vlist1, cnt + 1, Q2);
    act_k<<<gA64, 256, 0, stream>>>(Q2, Q3, ss + 256, ss + 320, cnt + 1, 64);
    dconv_w<64, 96, 25><<<dim3(sb2, 3), 256, 0, stream>>>(
        Q3, wdown1, amap1, vlist2, cnt + 2, R1);
    act_k<<<gA96, 256, 0, stream>>>(R1, R1, ss + 384, ss + 480, cnt + 2, 96);
    gconv_w<96, 0, 96, 25><<<dim3(sb2, 3), 256, 0, stream>>>(
        R1, nullptr, w2, amap2, vlist2, cnt + 2, R2);
    act_k<<<gA96, 256, 0, stream>>>(R2, R2, ss + 576, ss + 672, cnt + 2, 96);
    uconv_w<96, 64, 25><<<dim3(sb2, 2), 256, 0, stream>>>(
        R2, wup1, amap1, vlist2, cnt + 2, Q1);
    act_k<<<gA64, 256, 0, stream>>>(Q2, Q3, ss + 768, ss + 896, cnt + 1, 64);
    act_k<<<gA64, 256, 0, stream>>>(Q1, Q1, ss + 768 + 64, ss + 896 + 64, cnt + 1, 64);
    gconv_w<64, 64, 64, 50><<<dim3(sb1, 2), 256, 0, stream>>>(
        Q3, Q1, w1post, amap1, vlist1, cnt + 1, Q2);
    act_k<<<gA64, 256, 0, stream>>>(Q2, Q2, ss + 1024, ss + 1088, cnt + 1, 64);
    uconv_w<64, 32, 50><<<dim3(sb1, 1), 256, 0, stream>>>(
        Q2, wup0, amap0, vlist1, cnt + 1, P1);
    act_k<<<gA32, 256, 0, stream>>>(P2, P3, ss + 1152, ss + 1216, cnt + 0, 32);
    act_k<<<gA32, 256, 0, stream>>>(P1, P1, ss + 1152 + 32, ss + 1216 + 32, cnt + 0, 32);
    gconv_w<32, 32, 32, 100><<<dim3(sb0, 1), 256, 0, stream>>>(
        P3, P1, w0post, amap0, vlist0, cnt + 0, P2);
    final_k<<<gN, B, 0, stream>>>(coords, P2, amap0, ss + 1280, linW, linb, N, outp);
}

// Round 6
// 1969.138 us; speedup vs baseline: 1.4618x; 1.1821x over previous
//
#include <hip/hip_runtime.h>

// ---------------------------------------------------------------------------
// Sparse 3D U-Net forward (MI355X / gfx950), f32.
// Thread = slot (lane), waves split output channels (8 couts/wave, 32/block),
// gridDim.y splits COUT into 32-wide blocks. Weights staged to LDS per tap via
// __builtin_amdgcn_global_load_lds (16B, zero-VGPR DMA), double-buffered:
// issue tap t+1 -> compute tap t -> __syncthreads (drains vmcnt).
// Raster-ordered slots via deterministic prefix-scan compaction.
// ---------------------------------------------------------------------------

#define NVOX 100
#define EPSB 1e-4f
typedef unsigned long long u64;
#define DEVFN __device__ __forceinline__

// Stage one tap's [CTOT][32-cout slice] into lbuf (LDS), linear lane order.
// Slice element (ci, cg32+sub*4+{0..3}) <- w[ci*COUT + cg32 + sub*4 ...].
template<int CTOT, int COUT>
DEVFN void stage_tap(const float* __restrict__ wtap, int cg32,
                     float* __restrict__ lbuf, int wid, int lane)
{
    constexpr int IPW = CTOT / 32;   // global_load_lds issues per wave
#pragma unroll
    for (int i = 0; i < IPW; ++i) {
        const int chunk = wid * IPW + i;          // 64-float4 chunk index
        const int f4 = chunk * 64 + lane;         // this lane's float4 slot
        const int ci = f4 >> 3, sub = f4 & 7;
        const float* g = wtap + ci * COUT + cg32 + sub * 4;
        __builtin_amdgcn_global_load_lds(
            (const __attribute__((address_space(1))) void*)g,
            (__attribute__((address_space(3))) void*)(lbuf + chunk * 256),
            16, 0, 0);
    }
}

// acc[0..7] += row[ci] * wl[ci*32 + {0..7}]  (wl pre-offset by wave's 8 couts)
template<int CIN>
DEVFN void dorow8(const float* __restrict__ row, const float* __restrict__ wl,
                  float (&acc)[8])
{
#pragma unroll 4
    for (int c0 = 0; c0 < CIN; c0 += 4) {
        const float4 a = *reinterpret_cast<const float4*>(row + c0);
        const float av[4] = {a.x, a.y, a.z, a.w};
#pragma unroll
        for (int j = 0; j < 4; ++j) {
            const float4 w0 = *reinterpret_cast<const float4*>(wl + (c0 + j) * 32);
            const float4 w1 = *reinterpret_cast<const float4*>(wl + (c0 + j) * 32 + 4);
            acc[0] = fmaf(av[j], w0.x, acc[0]);
            acc[1] = fmaf(av[j], w0.y, acc[1]);
            acc[2] = fmaf(av[j], w0.z, acc[2]);
            acc[3] = fmaf(av[j], w0.w, acc[3]);
            acc[4] = fmaf(av[j], w1.x, acc[4]);
            acc[5] = fmaf(av[j], w1.y, acc[5]);
            acc[6] = fmaf(av[j], w1.z, acc[6]);
            acc[7] = fmaf(av[j], w1.w, acc[7]);
        }
    }
}

// 3x3x3 SAME submanifold conv (optional concat second input).
// grid = (ceil(cap/64), COUT/32); block = 256 (4 waves; wave w -> couts w*8..).
template<int CIN1, int CIN2, int COUT, int S>
__global__ __launch_bounds__(256)
void gconv_w(const float* __restrict__ inA, const float* __restrict__ inB,
             const float* __restrict__ w,
             const int* __restrict__ amap, const int* __restrict__ vlist,
             const int* __restrict__ cnt, float* __restrict__ out)
{
    constexpr int CTOT = CIN1 + CIN2;
    constexpr int F = CTOT * 32;       // LDS slice floats
    __shared__ float lw[2][F];
    const int tid = threadIdx.x;
    const int lane = tid & 63;
    const int wid = tid >> 6;
    const int cntv = *cnt;
    if (blockIdx.x * 64 >= cntv) return;
    const int slot = blockIdx.x * 64 + lane;
    const int cg32 = blockIdx.y * 32;
    const bool on = slot < cntv;
    int X = 0, Y = 0, Z = 0;
    if (on) { const int v = vlist[slot]; X = v % S; const int r = v / S; Y = r % S; Z = r / S; }
    float acc[8];
#pragma unroll
    for (int q = 0; q < 8; ++q) acc[q] = 0.f;
    stage_tap<CTOT, COUT>(w, cg32, lw[0], wid, lane);
    __syncthreads();
#pragma unroll 1
    for (int t = 0; t < 27; ++t) {
        if (t + 1 < 27)
            stage_tap<CTOT, COUT>(w + (size_t)(t + 1) * CTOT * COUT, cg32,
                                  lw[(t + 1) & 1], wid, lane);
        int ns = -1;
        if (on) {
            const int dz = t / 9 - 1, dy = (t / 3) % 3 - 1, dx = t % 3 - 1;
            const int nz = Z + dz, ny = Y + dy, nx = X + dx;
            if ((unsigned)nz < (unsigned)S && (unsigned)ny < (unsigned)S &&
                (unsigned)nx < (unsigned)S)
                ns = amap[(nz * S + ny) * S + nx];
        }
        if (ns >= 0) {
            const float* __restrict__ wl = &lw[t & 1][wid * 8];
            dorow8<CIN1>(inA + (size_t)ns * CIN1, wl, acc);
            if constexpr (CIN2 > 0)
                dorow8<CIN2>(inB + (size_t)ns * CIN2, wl + CIN1 * 32, acc);
        }
        __syncthreads();   // drains vmcnt (gl_lds) + orders buffer reuse
    }
    if (on) {
        float* __restrict__ op = out + (size_t)slot * COUT + cg32 + wid * 8;
        *reinterpret_cast<float4*>(op) = make_float4(acc[0], acc[1], acc[2], acc[3]);
        *reinterpret_cast<float4*>(op + 4) = make_float4(acc[4], acc[5], acc[6], acc[7]);
    }
}

// 2x2x2 stride-2 down conv, coarse-driven. grid = (ceil(capc/64), COUT/32).
template<int CIN, int COUT, int SC>
__global__ __launch_bounds__(256)
void dconv_w(const float* __restrict__ in, const float* __restrict__ w,
             const int* __restrict__ amap_f, const int* __restrict__ vlist_c,
             const int* __restrict__ cnt_c, float* __restrict__ out)
{
    constexpr int SF = SC * 2;
    constexpr int F = CIN * 32;
    __shared__ float lw[2][F];
    const int tid = threadIdx.x;
    const int lane = tid & 63;
    const int wid = tid >> 6;
    const int cntv = *cnt_c;
    if (blockIdx.x * 64 >= cntv) return;
    const int slot = blockIdx.x * 64 + lane;
    const int cg32 = blockIdx.y * 32;
    const bool on = slot < cntv;
    int X = 0, Y = 0, Z = 0;
    if (on) { const int v = vlist_c[slot]; X = v % SC; const int r = v / SC; Y = r % SC; Z = r / SC; }
    float acc[8];
#pragma unroll
    for (int q = 0; q < 8; ++q) acc[q] = 0.f;
    stage_tap<CIN, COUT>(w, cg32, lw[0], wid, lane);
    __syncthreads();
#pragma unroll 1
    for (int t = 0; t < 8; ++t) {
        if (t + 1 < 8)
            stage_tap<CIN, COUT>(w + (size_t)(t + 1) * CIN * COUT, cg32,
                                 lw[(t + 1) & 1], wid, lane);
        int ns = -1;
        if (on) {
            const int fz = 2 * Z + ((t >> 2) & 1);
            const int fy = 2 * Y + ((t >> 1) & 1);
            const int fx = 2 * X + (t & 1);
            ns = amap_f[(fz * SF + fy) * SF + fx];
        }
        if (ns >= 0)
            dorow8<CIN>(in + (size_t)ns * CIN, &lw[t & 1][wid * 8], acc);
        __syncthreads();
    }
    if (on) {
        float* __restrict__ op = out + (size_t)slot * COUT + cg32 + wid * 8;
        *reinterpret_cast<float4*>(op) = make_float4(acc[0], acc[1], acc[2], acc[3]);
        *reinterpret_cast<float4*>(op + 4) = make_float4(acc[4], acc[5], acc[6], acc[7]);
    }
}

// Transpose conv 2x2x2 stride 2, coarse-driven scatter; child t uses w[7-t].
template<int CIN, int COUT, int SC>
__global__ __launch_bounds__(256)
void uconv_w(const float* __restrict__ in, const float* __restrict__ w,
             const int* __restrict__ amap_f, const int* __restrict__ vlist_c,
             const int* __restrict__ cnt_c, float* __restrict__ out)
{
    constexpr int SF = SC * 2;
    constexpr int F = CIN * 32;
    __shared__ float lw[2][F];
    const int tid = threadIdx.x;
    const int lane = tid & 63;
    const int wid = tid >> 6;
    const int cntv = *cnt_c;
    if (blockIdx.x * 64 >= cntv) return;
    const int slot = blockIdx.x * 64 + lane;
    const int cg32 = blockIdx.y * 32;
    const bool on = slot < cntv;
    int X = 0, Y = 0, Z = 0;
    if (on) { const int v = vlist_c[slot]; X = v % SC; const int r = v / SC; Y = r % SC; Z = r / SC; }
    stage_tap<CIN, COUT>(w + (size_t)7 * CIN * COUT, cg32, lw[0], wid, lane);
    __syncthreads();
#pragma unroll 1
    for (int t = 0; t < 8; ++t) {
        if (t + 1 < 8)   // next child uses weight tap 7-(t+1) = 6-t
            stage_tap<CIN, COUT>(w + (size_t)(6 - t) * CIN * COUT, cg32,
                                 lw[(t + 1) & 1], wid, lane);
        int cs = -1;
        if (on) {
            const int fz = 2 * Z + ((t >> 2) & 1);
            const int fy = 2 * Y + ((t >> 1) & 1);
            const int fx = 2 * X + (t & 1);
            cs = amap_f[(fz * SF + fy) * SF + fx];
        }
        if (cs >= 0) {
            float acc[8];
#pragma unroll
            for (int q = 0; q < 8; ++q) acc[q] = 0.f;
            dorow8<CIN>(in + (size_t)slot * CIN, &lw[t & 1][wid * 8], acc);
            float* __restrict__ op = out + (size_t)cs * COUT + cg32 + wid * 8;
            *reinterpret_cast<float4*>(op) = make_float4(acc[0], acc[1], acc[2], acc[3]);
            *reinterpret_cast<float4*>(op + 4) = make_float4(acc[4], acc[5], acc[6], acc[7]);
        }
        __syncthreads();
    }
}

// First conv: dense 1-channel grid -> 32ch sparse (weights tiny, K$-resident).
template<int OSPLIT, int S>
__global__ __launch_bounds__(64 * OSPLIT)
void cin_k(const float* __restrict__ grid, const float* __restrict__ w,
           const int* __restrict__ vlist, const int* __restrict__ cnt,
           float* __restrict__ out)
{
    constexpr int OW = 32 / OSPLIT;
    const int wOff = __builtin_amdgcn_readfirstlane(threadIdx.x >> 6) * OW;
    const int slot = blockIdx.x * 64 + (threadIdx.x & 63);
    if (slot >= *cnt) return;
    const int v = vlist[slot];
    const int x = v % S;
    const int rem = v / S;
    const int y = rem % S;
    const int z = rem / S;
    float acc[OW];
#pragma unroll
    for (int c = 0; c < OW; ++c) acc[c] = 0.f;
#pragma unroll
    for (int t = 0; t < 27; ++t) {
        const int dz = t / 9 - 1, dy = (t / 3) % 3 - 1, dx = t % 3 - 1;
        const int nz = z + dz, ny = y + dy, nx = x + dx;
        if ((unsigned)nz >= (unsigned)S || (unsigned)ny >= (unsigned)S ||
            (unsigned)nx >= (unsigned)S) continue;
        const float val = grid[(nz * S + ny) * S + nx];
        const float* __restrict__ wp = w + t * 32 + wOff;
#pragma unroll
        for (int c = 0; c < OW; ++c) acc[c] = fmaf(val, wp[c], acc[c]);
    }
    float* __restrict__ op = out + (size_t)slot * 32 + wOff;
#pragma unroll
    for (int c = 0; c < OW; ++c) op[c] = acc[c];
}

// Elementwise bnrelu.
__global__ __launch_bounds__(256)
void act_k(const float* __restrict__ src, float* __restrict__ dst,
           const float* __restrict__ sc, const float* __restrict__ sh,
           const int* __restrict__ cnt, int C)
{
    const int f = (blockIdx.x * 256 + threadIdx.x) * 4;
    if (f >= (*cnt) * C) return;
    const int c0 = f % C;
    const float4 v = *reinterpret_cast<const float4*>(src + f);
    float4 o;
    o.x = fmaxf(fmaf(v.x, sc[c0 + 0], sh[c0 + 0]), 0.f);
    o.y = fmaxf(fmaf(v.y, sc[c0 + 1], sh[c0 + 1]), 0.f);
    o.z = fmaxf(fmaf(v.z, sc[c0 + 2], sh[c0 + 2]), 0.f);
    o.w = fmaxf(fmaf(v.w, sc[c0 + 3], sh[c0 + 3]), 0.f);
    *reinterpret_cast<float4*>(dst + f) = o;
}

// Final: bnrelu(y0, bnJ) then 32->3 linear per point.
__global__ __launch_bounds__(256)
void final_k(const int* __restrict__ coords, const float* __restrict__ y0,
             const int* __restrict__ amap0, const float* __restrict__ ssJ,
             const float* __restrict__ linW, const float* __restrict__ linb,
             int N, float* __restrict__ outp)
{
    const int n = blockIdx.x * blockDim.x + threadIdx.x;
    if (n >= N) return;
    const int i = coords[3 * n + 0];
    const int j = coords[3 * n + 1];
    const int k = coords[3 * n + 2];
    const int v = (i * NVOX + j) * NVOX + k;
    const int s = amap0[v];
    float a0 = linb[0], a1 = linb[1], a2 = linb[2];
    if (s >= 0) {
        const float* __restrict__ row = y0 + (size_t)s * 32;
#pragma unroll
        for (int c = 0; c < 32; ++c) {
            const float t = fmaxf(fmaf(row[c], ssJ[c], ssJ[32 + c]), 0.f);
            a0 = fmaf(t, linW[c * 3 + 0], a0);
            a1 = fmaf(t, linW[c * 3 + 1], a1);
            a2 = fmaf(t, linW[c * 3 + 2], a2);
        }
    }
    outp[3 * n + 0] = a0;
    outp[3 * n + 1] = a1;
    outp[3 * n + 2] = a2;
}

// Precompute per-channel scale/shift for all 10 BN layers.
__global__ void bn_prep(const float* __restrict__ A, const float* __restrict__ B,
                        const float* __restrict__ C, const float* __restrict__ D,
                        const float* __restrict__ E, const float* __restrict__ F,
                        const float* __restrict__ G, const float* __restrict__ H,
                        const float* __restrict__ I, const float* __restrict__ J,
                        float* __restrict__ ss)
{
    const float* bp[10] = {A, B, C, D, E, F, G, H, I, J};
    const int CH[10] = {32, 32, 64, 64, 96, 96, 128, 64, 64, 32};
    int idx = blockIdx.x * blockDim.x + threadIdx.x;
    if (idx >= 672) return;
    int l = 0, base = 0, off2 = 0;
    while (idx >= base + CH[l]) { base += CH[l]; off2 += 2 * CH[l]; ++l; }
    const int c = idx - base;
    const float* bn = bp[l];
    const int Cc = CH[l];
    const float g = bn[c], b = bn[Cc + c], mu = bn[2 * Cc + c], var = bn[3 * Cc + c];
    const float sc = g * rsqrtf(var + EPSB);
    ss[off2 + c] = sc;
    ss[off2 + Cc + c] = b - mu * sc;
}

__global__ __launch_bounds__(256)
void scatter_mark(const int* __restrict__ coords, const float* __restrict__ feats,
                  int N, float* __restrict__ grid, int* __restrict__ amap0)
{
    const int n = blockIdx.x * blockDim.x + threadIdx.x;
    if (n >= N) return;
    const int i = coords[3 * n + 0];
    const int j = coords[3 * n + 1];
    const int k = coords[3 * n + 2];
    const int v = (i * NVOX + j) * NVOX + k;
    atomicAdd(&grid[v], feats[n]);
    amap0[v] = -2;
}

template<int SC>
__global__ __launch_bounds__(256)
void flag_coarse(const int* __restrict__ amap_f, int* __restrict__ amap_c)
{
    constexpr int SF = SC * 2;
    const int v = blockIdx.x * blockDim.x + threadIdx.x;
    if (v >= SC * SC * SC) return;
    const int x = v % SC;
    const int rem = v / SC;
    const int y = rem % SC;
    const int z = rem / SC;
    bool any = false;
#pragma unroll
    for (int t = 0; t < 8; ++t) {
        const int fz = 2 * z + ((t >> 2) & 1);
        const int fy = 2 * y + ((t >> 1) & 1);
        const int fx = 2 * x + (t & 1);
        if (amap_f[(fz * SF + fy) * SF + fx] >= 0) any = true;
    }
    amap_c[v] = any ? -2 : -1;
}

// ---- deterministic raster-order compaction: count -> scan -> emit ----
__global__ __launch_bounds__(256)
void count_k(const int* __restrict__ flags, int V, int* __restrict__ counts)
{
    const int v = blockIdx.x * 256 + threadIdx.x;
    const bool act = (v < V) && (flags[v] == -2);
    const u64 m = __ballot(act);
    __shared__ int c[4];
    const int wid = threadIdx.x >> 6;
    if ((threadIdx.x & 63) == 0) c[wid] = __popcll(m);
    __syncthreads();
    if (threadIdx.x == 0) counts[blockIdx.x] = c[0] + c[1] + c[2] + c[3];
}

__global__ __launch_bounds__(1024)
void scan_k(int* __restrict__ counts, int nb, int* __restrict__ total)
{
    __shared__ int sums[1024];
    const int t = threadIdx.x;
    int v[4];
    int s = 0;
#pragma unroll
    for (int i = 0; i < 4; ++i) {
        const int idx = t * 4 + i;
        v[i] = (idx < nb) ? counts[idx] : 0;
        s += v[i];
    }
    sums[t] = s;
    __syncthreads();
    for (int d = 1; d < 1024; d <<= 1) {
        const int add = (t >= d) ? sums[t - d] : 0;
        __syncthreads();
        sums[t] += add;
        __syncthreads();
    }
    int base = (t > 0) ? sums[t - 1] : 0;
#pragma unroll
    for (int i = 0; i < 4; ++i) {
        const int idx = t * 4 + i;
        if (idx < nb) counts[idx] = base;
        base += v[i];
    }
    if (t == 1023) *total = sums[1023];
}

__global__ __launch_bounds__(256)
void emit_k(int* __restrict__ amap, int V, const int* __restrict__ offsets,
            int* __restrict__ vlist)
{
    const int v = blockIdx.x * 256 + threadIdx.x;
    const bool act = (v < V) && (amap[v] == -2);
    const u64 m = __ballot(act);
    __shared__ int wbase[4];
    const int wid = threadIdx.x >> 6;
    const int lane = threadIdx.x & 63;
    if (lane == 0) wbase[wid] = __popcll(m);
    __syncthreads();
    if (threadIdx.x == 0) {
        int s = 0;
#pragma unroll
        for (int i = 0; i < 4; ++i) { const int t = wbase[i]; wbase[i] = s; s += t; }
    }
    __syncthreads();
    if (act) {
        const int slot = offsets[blockIdx.x] + wbase[wid] +
                         __popcll(m & ((1ull << lane) - 1ull));
        amap[v] = slot;
        vlist[slot] = v;
    }
}

extern "C" void kernel_launch(void* const* d_in, const int* in_sizes, int n_in,
                              void* d_out, int out_size, void* d_ws, size_t ws_size,
                              hipStream_t stream) {
    const int*   coords = (const int*)d_in[0];
    const float* feats  = (const float*)d_in[1];
    const float* w_in   = (const float*)d_in[2];
    const float* w0a    = (const float*)d_in[3];
    const float* wdown0 = (const float*)d_in[4];
    const float* w1a    = (const float*)d_in[5];
    const float* wdown1 = (const float*)d_in[6];
    const float* w2     = (const float*)d_in[7];
    const float* wup1   = (const float*)d_in[8];
    const float* w1post = (const float*)d_in[9];
    const float* wup0   = (const float*)d_in[10];
    const float* w0post = (const float*)d_in[11];
    const float* linW = (const float*)d_in[22];
    const float* linb = (const float*)d_in[23];
    float* outp = (float*)d_out;

    const int N = in_sizes[1];            // 120000 points
    const int V0 = NVOX * NVOX * NVOX;
    const int V1 = 50 * 50 * 50;
    const int V2 = 25 * 25 * 25;
    const int cap0 = N;
    const int cap1 = 100000;
    const int cap2 = V2;

    char* ws = (char*)d_ws;
    size_t off = 0;
    auto alloc = [&](size_t bytes) -> void* {
        void* p = ws + off;
        off += (bytes + 255) & ~(size_t)255;
        return p;
    };
    int*   amap0  = (int*)alloc((size_t)V0 * 4);
    int*   vlist0 = (int*)alloc((size_t)cap0 * 4);
    int*   amap1  = (int*)alloc((size_t)V1 * 4);
    int*   vlist1 = (int*)alloc((size_t)cap1 * 4);
    int*   amap2  = (int*)alloc((size_t)V2 * 4);
    int*   vlist2 = (int*)alloc((size_t)cap2 * 4);
    int*   cnt    = (int*)alloc(3 * 4);
    int*   counts = (int*)alloc(4096 * 4);
    float* ss     = (float*)alloc(1344 * 4);
    float* grid   = (float*)alloc((size_t)V0 * 4);
    float* P1 = (float*)alloc((size_t)cap0 * 32 * 4);  // x/actA -> u0/actI2
    float* P2 = (float*)alloc((size_t)cap0 * 32 * 4);  // x0 -> y0
    float* P3 = (float*)alloc((size_t)cap0 * 32 * 4);  // actB -> actI1
    float* Q1 = (float*)alloc((size_t)cap1 * 64 * 4);  // d0/actC -> u1/actG2
    float* Q2 = (float*)alloc((size_t)cap1 * 64 * 4);  // x1 -> y1/actH
    float* Q3 = (float*)alloc((size_t)cap1 * 64 * 4);  // actD -> actG1
    float* R1 = (float*)alloc((size_t)cap2 * 96 * 4);  // d1/actE
    float* R2 = (float*)alloc((size_t)cap2 * 96 * 4);  // x2/actF
    if (off > ws_size) return;

    const int B = 256;
    const int gN  = (N + B - 1) / B;
    const int nb0 = (V0 + B - 1) / B;
    const int nb1 = (V1 + B - 1) / B;
    const int nb2 = (V2 + B - 1) / B;
    const int gA32 = (cap0 * 32 / 4 + 255) / 256;
    const int gA64 = (cap1 * 64 / 4 + 255) / 256;
    const int gA96 = (cap2 * 96 / 4 + 255) / 256;
    const int sb0 = (cap0 + 63) / 64;   // 1875 slot-blocks at L0
    const int sb1 = (cap1 + 63) / 64;   // 1563 at L1
    const int sb2 = (cap2 + 63) / 64;   // 245 at L2

    // ---- build phase ----
    hipMemsetAsync(amap0, 0xFF, (size_t)V0 * 4, stream);
    hipMemsetAsync(grid, 0, (size_t)V0 * 4, stream);
    bn_prep<<<3, 256, 0, stream>>>((const float*)d_in[12], (const float*)d_in[13],
                                   (const float*)d_in[14], (const float*)d_in[15],
                                   (const float*)d_in[16], (const float*)d_in[17],
                                   (const float*)d_in[18], (const float*)d_in[19],
                                   (const float*)d_in[20], (const float*)d_in[21], ss);
    scatter_mark<<<gN, B, 0, stream>>>(coords, feats, N, grid, amap0);
    count_k<<<nb0, B, 0, stream>>>(amap0, V0, counts);
    scan_k<<<1, 1024, 0, stream>>>(counts, nb0, cnt + 0);
    emit_k<<<nb0, B, 0, stream>>>(amap0, V0, counts, vlist0);
    flag_coarse<50><<<nb1, B, 0, stream>>>(amap0, amap1);
    count_k<<<nb1, B, 0, stream>>>(amap1, V1, counts);
    scan_k<<<1, 1024, 0, stream>>>(counts, nb1, cnt + 1);
    emit_k<<<nb1, B, 0, stream>>>(amap1, V1, counts, vlist1);
    flag_coarse<25><<<nb2, B, 0, stream>>>(amap1, amap2);
    count_k<<<nb2, B, 0, stream>>>(amap2, V2, counts);
    scan_k<<<1, 1024, 0, stream>>>(counts, nb2, cnt + 2);
    emit_k<<<nb2, B, 0, stream>>>(amap2, V2, counts, vlist2);

    // ---- network ----
    cin_k<2, 100><<<sb0, 128, 0, stream>>>(grid, w_in, vlist0, cnt + 0, P1);
    act_k<<<gA32, 256, 0, stream>>>(P1, P1, ss + 0, ss + 32, cnt + 0, 32);
    gconv_w<32, 0, 32, 100><<<dim3(sb0, 1), 256, 0, stream>>>(
        P1, nullptr, w0a, amap0, vlist0, cnt + 0, P2);
    act_k<<<gA32, 256, 0, stream>>>(P2, P3, ss + 64, ss + 96, cnt + 0, 32);
    dconv_w<32, 64, 50><<<dim3(sb1, 2), 256, 0, stream>>>(
        P3, wdown0, amap0, vlist1, cnt + 1, Q1);
    act_k<<<gA64, 256, 0, stream>>>(Q1, Q1, ss + 128, ss + 192, cnt + 1, 64);
    gconv_w<64, 0, 64, 50><<<dim3(sb1, 2), 256, 0, stream>>>(
        Q1, nullptr, w1a, amap1, vlist1, cnt + 1, Q2);
    act_k<<<gA64, 256, 0, stream>>>(Q2, Q3, ss + 256, ss + 320, cnt + 1, 64);
    dconv_w<64, 96, 25><<<dim3(sb2, 3), 256, 0, stream>>>(
        Q3, wdown1, amap1, vlist2, cnt + 2, R1);
    act_k<<<gA96, 256, 0, stream>>>(R1, R1, ss + 384, ss + 480, cnt + 2, 96);
    gconv_w<96, 0, 96, 25><<<dim3(sb2, 3), 256, 0, stream>>>(
        R1, nullptr, w2, amap2, vlist2, cnt + 2, R2);
    act_k<<<gA96, 256, 0, stream>>>(R2, R2, ss + 576, ss + 672, cnt + 2, 96);
    uconv_w<96, 64, 25><<<dim3(sb2, 2), 256, 0, stream>>>(
        R2, wup1, amap1, vlist2, cnt + 2, Q1);
    act_k<<<gA64, 256, 0, stream>>>(Q2, Q3, ss + 768, ss + 896, cnt + 1, 64);
    act_k<<<gA64, 256, 0, stream>>>(Q1, Q1, ss + 768 + 64, ss + 896 + 64, cnt + 1, 64);
    gconv_w<64, 64, 64, 50><<<dim3(sb1, 2), 256, 0, stream>>>(
        Q3, Q1, w1post, amap1, vlist1, cnt + 1, Q2);
    act_k<<<gA64, 256, 0, stream>>>(Q2, Q2, ss + 1024, ss + 1088, cnt + 1, 64);
    uconv_w<64, 32, 50><<<dim3(sb1, 1), 256, 0, stream>>>(
        Q2, wup0, amap0, vlist1, cnt + 1, P1);
    act_k<<<gA32, 256, 0, stream>>>(P2, P3, ss + 1152, ss + 1216, cnt + 0, 32);
    act_k<<<gA32, 256, 0, stream>>>(P1, P1, ss + 1152 + 32, ss + 1216 + 32, cnt + 0, 32);
    gconv_w<32, 32, 32, 100><<<dim3(sb0, 1), 256, 0, stream>>>(
        P3, P1, w0post, amap0, vlist0, cnt + 0, P2);
    final_k<<<gN, B, 0, stream>>>(coords, P2, amap0, ss + 1280, linW, linb, N, outp);
}